// Round 10
// baseline (223.222 us; speedup 1.0000x reference)
//
#include <hip/hip_runtime.h>
#include <stdint.h>

typedef unsigned short u16;
typedef __attribute__((ext_vector_type(8))) short bf16x8;
typedef __attribute__((ext_vector_type(4))) float f32x4;

#define MFMA(a,b,c) __builtin_amdgcn_mfma_f32_16x16x32_bf16((a),(b),(c),0,0,0)

static constexpr int S  = 4096;
static constexpr int D  = 768;
static constexpr int H  = 12;
static constexpr int HD = 64;

// float -> bf16 round-nearest-even
__device__ __forceinline__ u16 f2b(float f){
  union { float f; unsigned u; } v; v.f = f;
  unsigned r = (v.u + 0x7fffu + ((v.u >> 16) & 1u)) >> 16;
  return (u16)r;
}

// pack 2 floats -> 2 bf16 (truncation) in ONE v_perm_b32
__device__ __forceinline__ unsigned pack_bf16_trunc(float a, float b){
  return __builtin_amdgcn_perm(__float_as_uint(b), __float_as_uint(a), 0x07060302u);
}

// async global->LDS 16B per lane (DMA path, no VGPR round-trip)
__device__ __forceinline__ void cp16(const u16* g, u16* l){
  __builtin_amdgcn_global_load_lds(
      (const __attribute__((address_space(1))) unsigned int*)g,
      (__attribute__((address_space(3))) unsigned int*)l, 16, 0, 0);
}

// 4-lane (quad) butterfly transpose via gfx950 permlane swaps (4 VALU instrs).
__device__ __forceinline__ bf16x8 quad_transpose(unsigned M0, unsigned M1,
                                                 unsigned M2, unsigned M3){
  auto r0 = __builtin_amdgcn_permlane32_swap(M0, M2, false, false);
  auto r1 = __builtin_amdgcn_permlane32_swap(M1, M3, false, false);
  auto s0 = __builtin_amdgcn_permlane16_swap(r0[0], r0[1], false, false);
  auto s1 = __builtin_amdgcn_permlane16_swap(r1[0], r1[1], false, false);
  union { unsigned u[4]; bf16x8 v; } r;
  r.u[0] = s0[0];
  r.u[1] = s1[0];
  r.u[2] = s0[1];
  r.u[3] = s1[1];
  return r.v;
}

// ---------------- fused cast fp32 -> bf16 for x + 4 weights ----------------
static constexpr int NX4 = (2 * S * D) / 4;   // 1572864
static constexpr int NW4 = (D * D) / 4;       // 147456
__global__ void castall(const float* __restrict__ x,  const float* __restrict__ wq,
                        const float* __restrict__ wk, const float* __restrict__ wv,
                        const float* __restrict__ wo,
                        u16* __restrict__ xb,  u16* __restrict__ wqb,
                        u16* __restrict__ wkb, u16* __restrict__ wvb,
                        u16* __restrict__ wob){
  int i = blockIdx.x * 256 + threadIdx.x;
  const float* s; u16* d; int off;
  if (i < NX4) { s = x; d = xb; off = i; }
  else {
    int j = i - NX4; int wsel = j / NW4; off = j - wsel * NW4;
    if (wsel >= 4) return;
    s = (wsel == 0) ? wq : (wsel == 1) ? wk : (wsel == 2) ? wv : wo;
    d = (wsel == 0) ? wqb : (wsel == 1) ? wkb : (wsel == 2) ? wvb : wob;
  }
  float4 v = ((const float4*)s)[off];
  uint2 o;
  o.x = (unsigned)f2b(v.x) | ((unsigned)f2b(v.y) << 16);
  o.y = (unsigned)f2b(v.z) | ((unsigned)f2b(v.w) << 16);
  ((uint2*)d)[off] = o;
}

// ---------------- QKV GEMM: BK=32 double-buffered, counted vmcnt (R9 pipeline ported) ----------------
// Old: BK=64 single-buffer, vmcnt(0)-in-__syncthreads drain every one of 12 K-iters (the same
// serializer R8/R9 diagnosed in attn). New: BK=32 -> dbuf fits the SAME 32KB LDS (no residency
// loss, R7 lesson): As[2][128x32]+Bs[2][128x32]. Per iter: stage next K-slice (4 cp16) ->
// s_waitcnt vmcnt(4) (current slice ready, next in flight) -> s_barrier -> 16 MFMA -> s_barrier.
// Swizzle for 4-chunk rows: slot = chunk ^ ((row>>1)&3); 16 lanes -> 2/bank (free, m136).
// launch_bounds(256,4): ~115 live VGPR fits 128 -> 4 blocks/CU against the 1152-block queue.
__global__ __launch_bounds__(256, 4) void qkv_gemm(
    const u16* __restrict__ xb, const u16* __restrict__ wq, const u16* __restrict__ wk,
    const u16* __restrict__ wv, u16* __restrict__ Qb, u16* __restrict__ Kb, u16* __restrict__ Vt)
{
  __shared__ __align__(16) u16 As[2][128 * 32];   // 2x8 KB
  __shared__ __align__(16) u16 Bs[2][128 * 32];   // 2x8 KB
  const int t = threadIdx.x;
  const int mblk = blockIdx.x, nblk = blockIdx.y, z = blockIdx.z;
  const u16* W = (z == 0) ? wq : (z == 1) ? wk : wv;
  const int w = t >> 6, lane = t & 63, quad = lane >> 4, l16 = lane & 15;
  const int wr = w >> 1, wc = w & 1;

  f32x4 acc[4][4];
  #pragma unroll
  for (int i = 0; i < 4; i++)
    #pragma unroll
    for (int j = 0; j < 4; j++) acc[i][j] = (f32x4){0.f, 0.f, 0.f, 0.f};

  // staging: 512 slots/tile; thread t covers slots t (row t>>2) and t+256 (row 64+(t>>2)).
  // slot cs holds global chunk cs ^ ((row>>1)&3); rows r0 and r0+64 share the XOR.
  const int r0 = t >> 2;
  const int gc = (t & 3) ^ ((r0 >> 1) & 3);
  const u16* gA = xb + (size_t)(mblk * 128) * D;
  const u16* gB = W  + (size_t)(nblk * 128) * D;

  auto stage = [&](int it, int d){
    const int k0 = it * 32;
    cp16(gA + (size_t)r0 * D        + k0 + gc * 8, &As[d][0] + t * 8);
    cp16(gA + (size_t)(r0 + 64) * D + k0 + gc * 8, &As[d][0] + (t + 256) * 8);
    cp16(gB + (size_t)r0 * D        + k0 + gc * 8, &Bs[d][0] + t * 8);
    cp16(gB + (size_t)(r0 + 64) * D + k0 + gc * 8, &Bs[d][0] + (t + 256) * 8);
  };

  stage(0, 0);                                    // prologue
  const int fA = (quad ^ ((l16 >> 1) & 3)) * 8;   // fragment slot offset (row>>1 == l16>>1 mod 4)

  for (int it = 0; it < 24; ++it) {
    const int cur = it & 1;
    const bool last = (it == 23);
    if (!last) {
      stage(it + 1, cur ^ 1);
      asm volatile("s_waitcnt vmcnt(4)\ns_barrier" ::: "memory");
    } else {
      asm volatile("s_waitcnt vmcnt(0)\ns_barrier" ::: "memory");
    }
    bf16x8 af[4], bfr[4];
    #pragma unroll
    for (int mt = 0; mt < 4; mt++)
      af[mt]  = *(const bf16x8*)(&As[cur][0] + (wr * 64 + mt * 16 + l16) * 32 + fA);
    #pragma unroll
    for (int nt = 0; nt < 4; nt++)
      bfr[nt] = *(const bf16x8*)(&Bs[cur][0] + (wc * 64 + nt * 16 + l16) * 32 + fA);
    #pragma unroll
    for (int mt = 0; mt < 4; mt++)
      #pragma unroll
      for (int nt = 0; nt < 4; nt++)
        acc[mt][nt] = MFMA(af[mt], bfr[nt], acc[mt][nt]);
    asm volatile("s_barrier" ::: "memory");
  }

  const float qscale = 0.18033688011112042f;  // 0.125 * log2(e)
  #pragma unroll
  for (int mt = 0; mt < 4; mt++) {
    int m0 = mblk * 128 + wr * 64 + mt * 16 + quad * 4;
    #pragma unroll
    for (int nt = 0; nt < 4; nt++) {
      int n = nblk * 128 + wc * 64 + nt * 16 + l16;
      int h = n >> 6, hd = n & 63;
      if (z == 2) {
        int b = m0 >> 12, s0 = m0 & 4095;
        u16* p = Vt + (((size_t)(b * H + h) * HD + hd)) * S + s0;
        uint2 pk;
        pk.x = (unsigned)f2b(acc[mt][nt][0]) | ((unsigned)f2b(acc[mt][nt][1]) << 16);
        pk.y = (unsigned)f2b(acc[mt][nt][2]) | ((unsigned)f2b(acc[mt][nt][3]) << 16);
        *(uint2*)p = pk;
      } else {
        u16* dst = (z == 0) ? Qb : Kb;
        float sc = (z == 0) ? qscale : 1.0f;
        #pragma unroll
        for (int r = 0; r < 4; r++) {
          int m = m0 + r; int b = m >> 12, s = m & 4095;
          dst[((size_t)(b * H + h) * S + s) * HD + hd] = f2b(acc[mt][nt][r] * sc);
        }
      }
    }
  }
}

// ---------------- flash attention: 64-key dbuf tiles + counted vmcnt at 4 blocks/CU (R9, best) ----------------
__global__ __launch_bounds__(256, 2) void attn(
    const u16* __restrict__ Qb, const u16* __restrict__ Kb,
    const u16* __restrict__ Vt, u16* __restrict__ ctx)
{
  __shared__ __align__(16) u16 Ks[2][64 * 64];   // K tile [key][hd], chunk c at c^(key&7)  : 2x8 KB
  __shared__ __align__(16) u16 Vts[2][64 * 64];  // V^T tile [hd][key], chunk c at c^(hd&7) : 2x8 KB
  __shared__ float Lbuf[2][2][16];               // lsum exchange: [wq][qt][l16]
  const int t = threadIdx.x, w = t >> 6, lane = t & 63, quad = lane >> 4, l16 = lane & 15;
  const int l7 = l16 & 7;
  const int wq = w >> 1, wk = w & 1;             // query-half (32q), key-half (32k of 64) of wave

  const int p       = (int)blockIdx.x;
  const int bh      = p % 24;                    // p%8 == bh%8 -> XCD affinity
  const int qtile64 = 63 - p / 24;               // longest-first dispatch order
  const int q0 = qtile64 * 64;
  const int nt = qtile64 + 1;                    // number of 64-key tiles

  const u16* Qh = Qb + (size_t)bh * S * HD;
  const u16* Kh = Kb + (size_t)bh * S * HD;
  const u16* Vh = Vt + (size_t)bh * S * HD;      // [64][4096]
  const int b = bh / H, h = bh % H;

  // Q fragments (B-operand): lane holds Q[q0+wq*32+qt*16+l16][ksh*32+quad*8 ..+7]
  bf16x8 qf[2][2];
  #pragma unroll
  for (int qt = 0; qt < 2; qt++)
    #pragma unroll
    for (int ksh = 0; ksh < 2; ksh++)
      qf[qt][ksh] = *(const bf16x8*)(Qh + (size_t)(q0 + wq * 32 + qt * 16 + l16) * HD + ksh * 32 + quad * 8);
  // drain Q loads so staging vmcnt arithmetic is exact from here on
  asm volatile("s_waitcnt vmcnt(0)" ::: "memory");

  // O^T acc: row=hd (co*16+quad*4+r), col=query (qt*16+l16); partial over this wave's keys
  f32x4 ao[2][4];
  #pragma unroll
  for (int qt = 0; qt < 2; qt++)
    #pragma unroll
    for (int co = 0; co < 4; co++) ao[qt][co] = (f32x4){0.f, 0.f, 0.f, 0.f};
  float lsum[2] = {0.f, 0.f};

  // DMA slot descriptors: 512 slots each for K and V (2/thread each).
  // slot s -> row s>>3 (key for K, hd for V), chunk (s&7)^(row&7); rows r0, r0+32 share chunk.
  const int r0 = t >> 3;
  const int c0 = (t & 7) ^ (r0 & 7);

  // stage 64-key tile starting at kv into buffer d (4 cp16 per thread)
  auto stage = [&](int kv, int d){
    cp16(Kh + (size_t)(kv + r0)      * HD + c0 * 8, &Ks[d][0] + t * 8);
    cp16(Kh + (size_t)(kv + r0 + 32) * HD + c0 * 8, &Ks[d][0] + (t + 256) * 8);
    cp16(Vh + (size_t)r0 * S        + kv + c0 * 8, &Vts[d][0] + t * 8);
    cp16(Vh + (size_t)(r0 + 32) * S + kv + c0 * 8, &Vts[d][0] + (t + 256) * 8);
  };

  stage(0, 0);                                   // prologue

  for (int it = 0; it < nt; ++it) {
    const int cur = it & 1;
    const bool diag = (it == nt - 1);
    if (!diag) stage((it + 1) * 64, cur ^ 1);    // next tile's 4 loads
    // wait for THIS tile's 4 loads only; leave next tile's in flight across the barrier
    if (!diag) asm volatile("s_waitcnt vmcnt(4)\ns_barrier" ::: "memory");
    else       asm volatile("s_waitcnt vmcnt(0)\ns_barrier" ::: "memory");

    // key_rel = wk*32+kt*16+quad*4+r, query_rel = wq*32+qt*16+l16 (within this 64x64 diag tile)
    const bool skipall = diag && (wk == 1) && (wq == 0);  // keys all above queries
    const bool mdiag   = diag && (wk == wq);              // element-mask region

    if (!skipall) {
      const u16* Kc = &Ks[cur][0];
      const u16* Vc = &Vts[cur][0];
      unsigned pA[2][2], pB[2][2];               // [qt][ktL]: packed bf16 pairs
      #pragma unroll
      for (int ktL = 0; ktL < 2; ktL++) {        // two 16-key tiles of this wave's 32 keys
        const int krw = wk * 32 + ktL * 16 + l16;
        bf16x8 kf0 = *(const bf16x8*)(Kc + krw * 64 + ((0 + quad) ^ l7) * 8);
        bf16x8 kf1 = *(const bf16x8*)(Kc + krw * 64 + ((4 + quad) ^ l7) * 8);
        #pragma unroll
        for (int qt = 0; qt < 2; qt++) {
          f32x4 s0 = (f32x4){0.f, 0.f, 0.f, 0.f};
          __builtin_amdgcn_s_setprio(1);
          s0 = MFMA(kf0, qf[qt][0], s0);
          s0 = MFMA(kf1, qf[qt][1], s0);
          __builtin_amdgcn_s_setprio(0);
          if (mdiag) {
            const int qoff = (qt - ktL) * 16 + l16;   // wq==wk cancels the *32 terms
            #pragma unroll
            for (int r = 0; r < 4; r++)
              s0[r] = (quad * 4 + r > qoff) ? -1e30f : s0[r];
          }
          float p0 = __builtin_amdgcn_exp2f(s0[0]);
          float p1 = __builtin_amdgcn_exp2f(s0[1]);
          float p2 = __builtin_amdgcn_exp2f(s0[2]);
          float p3 = __builtin_amdgcn_exp2f(s0[3]);
          lsum[qt] += (p0 + p1) + (p2 + p3);
          pA[qt][ktL] = pack_bf16_trunc(p0, p1);
          pB[qt][ktL] = pack_bf16_trunc(p2, p3);
        }
      }
      // in-register P^T fragments for this wave's 32-key group
      bf16x8 pf[2];
      #pragma unroll
      for (int qt = 0; qt < 2; qt++)
        pf[qt] = quad_transpose(pA[qt][0], pB[qt][0], pA[qt][1], pB[qt][1]);
      // O^T += V^T P^T
      __builtin_amdgcn_s_setprio(1);
      #pragma unroll
      for (int co = 0; co < 4; co++) {
        const int vrw = co * 16 + l16;
        bf16x8 vf = *(const bf16x8*)(Vc + vrw * 64 + ((wk * 4 + quad) ^ (vrw & 7)) * 8);
        #pragma unroll
        for (int qt = 0; qt < 2; qt++)
          ao[qt][co] = MFMA(vf, pf[qt], ao[qt][co]);
      }
      __builtin_amdgcn_s_setprio(0);
    }
    asm volatile("s_barrier" ::: "memory");      // all waves done reading buf[cur]
  }

  // ---- epilogue: quad-reduce lsum, then cross-wave (wk) reduction of O and lsum ----
  #pragma unroll
  for (int qt = 0; qt < 2; qt++) {
    float v = lsum[qt];
    v += __shfl_xor(v, 16, 64);
    v += __shfl_xor(v, 32, 64);
    lsum[qt] = v;
  }

  // loop's final s_barrier ensures all compute done -> safe to reuse buffers as scratch
  float* red = wq ? (float*)&Vts[0][0] : (float*)&Ks[0][0];   // 8KB scratch per query-half pair
  if (wk == 1) {
    #pragma unroll
    for (int qt = 0; qt < 2; qt++)
      #pragma unroll
      for (int co = 0; co < 4; co++)
        *(f32x4*)(red + ((qt * 4 + co) * 64 + lane) * 4) = ao[qt][co];
    if (lane < 16) {
      #pragma unroll
      for (int qt = 0; qt < 2; qt++) Lbuf[wq][qt][lane] = lsum[qt];
    }
  }
  __syncthreads();
  if (wk == 0) {
    #pragma unroll
    for (int qt = 0; qt < 2; qt++) {
      float tot = lsum[qt] + Lbuf[wq][qt][l16];
      float inv = 1.0f / tot;
      int token = b * S + q0 + wq * 32 + qt * 16 + l16;
      #pragma unroll
      for (int co = 0; co < 4; co++) {
        f32x4 pr = *(const f32x4*)(red + ((qt * 4 + co) * 64 + lane) * 4);
        f32x4 sv = ao[qt][co] + pr;
        uint2 pk;
        pk.x = (unsigned)f2b(sv[0] * inv) | ((unsigned)f2b(sv[1] * inv) << 16);
        pk.y = (unsigned)f2b(sv[2] * inv) | ((unsigned)f2b(sv[3] * inv) << 16);
        *(uint2*)(ctx + (size_t)token * D + h * HD + co * 16 + quad * 4) = pk;
      }
    }
  }
}

// ---------------- output projection: BK=32 dbuf + counted vmcnt (same pipeline) ----------------
__global__ __launch_bounds__(256, 2) void out_gemm(
    const u16* __restrict__ ctx, const u16* __restrict__ wo,
    const float* __restrict__ bias, float* __restrict__ out)
{
  __shared__ __align__(16) u16 As[2][128 * 32];
  __shared__ __align__(16) u16 Bs[2][128 * 32];
  const int t = threadIdx.x;
  const int mblk = blockIdx.x, nblk = blockIdx.y;
  const int w = t >> 6, lane = t & 63, quad = lane >> 4, l16 = lane & 15;
  const int wr = w >> 1, wc = w & 1;

  f32x4 acc[4][4];
  #pragma unroll
  for (int i = 0; i < 4; i++)
    #pragma unroll
    for (int j = 0; j < 4; j++) acc[i][j] = (f32x4){0.f, 0.f, 0.f, 0.f};

  const int r0 = t >> 2;
  const int gc = (t & 3) ^ ((r0 >> 1) & 3);
  const u16* gA = ctx + (size_t)(mblk * 128) * D;
  const u16* gB = wo  + (size_t)(nblk * 128) * D;

  auto stage = [&](int it, int d){
    const int k0 = it * 32;
    cp16(gA + (size_t)r0 * D        + k0 + gc * 8, &As[d][0] + t * 8);
    cp16(gA + (size_t)(r0 + 64) * D + k0 + gc * 8, &As[d][0] + (t + 256) * 8);
    cp16(gB + (size_t)r0 * D        + k0 + gc * 8, &Bs[d][0] + t * 8);
    cp16(gB + (size_t)(r0 + 64) * D + k0 + gc * 8, &Bs[d][0] + (t + 256) * 8);
  };

  stage(0, 0);
  const int fA = (quad ^ ((l16 >> 1) & 3)) * 8;

  for (int it = 0; it < 24; ++it) {
    const int cur = it & 1;
    const bool last = (it == 23);
    if (!last) {
      stage(it + 1, cur ^ 1);
      asm volatile("s_waitcnt vmcnt(4)\ns_barrier" ::: "memory");
    } else {
      asm volatile("s_waitcnt vmcnt(0)\ns_barrier" ::: "memory");
    }
    bf16x8 af[4], bfr[4];
    #pragma unroll
    for (int mt = 0; mt < 4; mt++)
      af[mt]  = *(const bf16x8*)(&As[cur][0] + (wr * 64 + mt * 16 + l16) * 32 + fA);
    #pragma unroll
    for (int nt = 0; nt < 4; nt++)
      bfr[nt] = *(const bf16x8*)(&Bs[cur][0] + (wc * 64 + nt * 16 + l16) * 32 + fA);
    #pragma unroll
    for (int mt = 0; mt < 4; mt++)
      #pragma unroll
      for (int nt = 0; nt < 4; nt++)
        acc[mt][nt] = MFMA(af[mt], bfr[nt], acc[mt][nt]);
    asm volatile("s_barrier" ::: "memory");
  }

  #pragma unroll
  for (int mt = 0; mt < 4; mt++) {
    int m0 = mblk * 128 + wr * 64 + mt * 16 + quad * 4;
    #pragma unroll
    for (int nt = 0; nt < 4; nt++) {
      int n = nblk * 128 + wc * 64 + nt * 16 + l16;
      float bv = bias[n];
      #pragma unroll
      for (int r = 0; r < 4; r++)
        out[(size_t)(m0 + r) * D + n] = acc[mt][nt][r] + bv;
    }
  }
}

// ---------------- host launch ----------------
extern "C" void kernel_launch(void* const* d_in, const int* in_sizes, int n_in,
                              void* d_out, int out_size, void* d_ws, size_t ws_size,
                              hipStream_t stream) {
  const float* x    = (const float*)d_in[0];
  const float* wq   = (const float*)d_in[1];
  const float* wk   = (const float*)d_in[2];
  const float* wv   = (const float*)d_in[3];
  const float* wo   = (const float*)d_in[4];
  const float* bo   = (const float*)d_in[5];
  float* out = (float*)d_out;

  u16* ws = (u16*)d_ws;
  const size_t NX = (size_t)2 * S * D;      // 6291456
  const size_t NW = (size_t)D * D;          // 589824
  u16* xb  = ws;                // [8192][768]; reused as ctx after qkv_gemm consumes it
  u16* wqb = ws + NX;
  u16* wkb = wqb + NW;
  u16* wvb = wkb + NW;
  u16* wob = wvb + NW;
  u16* Qb  = wob + NW;          // [2][12][4096][64] bf16 (pre-scaled by 0.125*log2e)
  u16* Kb  = Qb + NX;           // bf16
  u16* Vt  = Kb + NX;           // [2][12][64][4096] bf16
  u16* ctx = xb;

  const int total4 = NX4 + 4 * NW4;
  castall<<<(total4 + 255) / 256, 256, 0, stream>>>(x, wq, wk, wv, wo, xb, wqb, wkb, wvb, wob);

  qkv_gemm<<<dim3(64, 6, 3), 256, 0, stream>>>(xb, wqb, wkb, wvb, Qb, Kb, Vt);
  attn<<<dim3(1536), 256, 0, stream>>>(Qb, Kb, Vt, ctx);
  out_gemm<<<dim3(64, 6), 256, 0, stream>>>(ctx, wob, bo, out);
}